// Round 4
// baseline (265.297 us; speedup 1.0000x reference)
//
#include <hip/hip_runtime.h>
#include <hip/hip_bf16.h>
#include <cmath>

#define B     128
#define CIN   8
#define COUT  64
#define K     33
#define KP    36           // padded taps (288 = 9 * 32)
#define KKD   (KP * CIN)   // 288 reduction length, kk = tap*8 + ci
#define NSL   (KKD / 32)   // 9 MFMA K-slices
#define L     4096
#define PAD   16
#define HID   128
#define NW    3

#define TL    512          // l-tile per block
#define NROW  (TL + KP)    // 548 xT rows (pos range [l0-16, l0+TL+19])

typedef __attribute__((ext_vector_type(8))) short short8;
typedef __attribute__((ext_vector_type(4))) float f32x4;

__device__ __forceinline__ float softplusf(float v) {
    return (v > 20.f) ? v : log1pf(expf(v));
}

// ---------------------------------------------------------------------------
// Fused prologue: blocks 0..127 = agent (stats + MLP -> action),
//                 blocks 128..133 = wavelet bank build (bf16, padded layout).
// argmax(q) == argmax(a): value head & a.mean() are uniform across NW -> skip.
// ---------------------------------------------------------------------------
__global__ __launch_bounds__(256) void prologue_kernel(
    const float* __restrict__ x,
    const float* __restrict__ fw, const float* __restrict__ fb,
    const float* __restrict__ aw1, const float* __restrict__ ab1,
    const float* __restrict__ aw2, const float* __restrict__ ab2,
    const float* __restrict__ sp,
    int* __restrict__ actions, __hip_bfloat16* __restrict__ bankbf)
{
    const int tid = threadIdx.x;

    if (blockIdx.x < B) {
        // ---------------- agent path ----------------
        const int b = blockIdx.x;
        __shared__ float st[2 * CIN];
        __shared__ float h[HID];
        __shared__ float ha[HID];

        const int ci  = tid >> 5;
        const int sub = tid & 31;
        const float* xp = x + ((size_t)b * CIN + ci) * L;
        float s = 0.f, ss = 0.f;
        for (int j = sub; j < L / 4; j += 32) {
            float4 v = ((const float4*)xp)[j];
            s  += v.x + v.y + v.z + v.w;
            ss += v.x * v.x + v.y * v.y + v.z * v.z + v.w * v.w;
        }
        for (int m = 16; m; m >>= 1) {
            s  += __shfl_xor(s,  m);
            ss += __shfl_xor(ss, m);
        }
        if (sub == 0) {
            float mean = s / (float)L;
            float var  = fmaxf(ss - s * mean, 0.f) / (float)(L - 1);
            st[ci]       = mean;
            st[CIN + ci] = sqrtf(var);
        }
        __syncthreads();

        const int j = tid;
        if (j < HID) {
            float acc = fb[j];
            #pragma unroll
            for (int i = 0; i < 2 * CIN; ++i) acc = fmaf(st[i], fw[i * HID + j], acc);
            h[j] = fmaxf(acc, 0.f);
        }
        __syncthreads();
        if (j < HID) {
            float acc2 = ab1[j];
            for (int i = 0; i < HID; ++i) acc2 = fmaf(h[i], aw1[i * HID + j], acc2);
            ha[j] = fmaxf(acc2, 0.f);
        }
        __syncthreads();
        if (j == 0) {
            float best = -1e30f; int bi = 0;
            for (int w = 0; w < NW; ++w) {
                float a = ab2[w];
                for (int i = 0; i < HID; ++i) a = fmaf(ha[i], aw2[i * NW + w], a);
                if (a > best) { best = a; bi = w; }
            }
            actions[b] = bi;
        }
    } else {
        // ---------------- bank path ----------------
        const int t = (blockIdx.x - B) * 256 + tid;   // 6*256 = 1536 = NW*COUT*CIN
        if (t >= NW * COUT * CIN) return;
        const int nw = t >> 9;
        const int co = (t >> 3) & 63;
        const int ci = t & 7;

        const float p = sp[(co * CIN + ci) * NW + nw];
        const float scale = softplusf(p) + 1e-6f;

        float ker[K];
        float mean = 0.f;
        #pragma unroll
        for (int k = 0; k < K; ++k) {
            float g  = (float)(k - K / 2);
            float xi = g / scale;
            float v;
            if (nw == 0) {
                v = expf(-0.5f * xi * xi) * cosf(5.f * xi);
            } else if (nw == 1) {
                v = 0.8673250705840776f * (1.f - xi * xi) * expf(-0.5f * xi * xi);
            } else {
                float sgn = (g > 0.f) ? 1.f : ((g < 0.f) ? -1.f : 0.f);
                v = sgn * expf(-fabsf(xi));
            }
            ker[k] = v; mean += v;
        }
        mean *= (1.f / (float)K);
        float nrm = 0.f;
        #pragma unroll
        for (int k = 0; k < K; ++k) { ker[k] -= mean; nrm += ker[k] * ker[k]; }
        const float inv = 1.f / (sqrtf(nrm) + 1e-6f);

        __hip_bfloat16* dst = bankbf + ((size_t)(nw * COUT + co)) * KKD + ci;
        #pragma unroll
        for (int k = 0; k < K; ++k) dst[k * CIN] = __float2bfloat16(ker[k] * inv);
        #pragma unroll
        for (int k = K; k < KP; ++k) dst[k * CIN] = __float2bfloat16(0.f);
    }
}

// ---------------------------------------------------------------------------
// Conv: implicit GEMM via MFMA 16x16x32 bf16 + soft shrinkage.
//   D[co, l] = sum_kk W[co, kk] * X[kk, l],  kk = tap*8 + ci
//   X[kk, l] read from LDS xT[pos][ci] (16B rows).
// 8 waves / block: wave w -> co-pair p = w&1 (tiles 2p,2p+1),
//                  l-quarter q = w>>1 (128 l). aQ[2][9] = 72 VGPR.
// ---------------------------------------------------------------------------
__global__ __launch_bounds__(512, 4) void conv_kernel(
    const float* __restrict__ x, const __hip_bfloat16* __restrict__ bankbf,
    const int* __restrict__ actions, const float* __restrict__ threshold,
    float* __restrict__ out)
{
    const int b  = blockIdx.y;
    const int l0 = blockIdx.x * TL;
    const int tid  = threadIdx.x;
    const int lane = tid & 63;
    const int w    = tid >> 6;        // wave id 0..7
    const int p    = w & 1;           // co-pair: tiles 2p, 2p+1
    const int q    = w >> 1;          // l-quarter 0..3
    const int g    = lane >> 4;       // lane group 0..3
    const int ln   = lane & 15;

    __shared__ short8 xT[NROW];       // [pos][ci] bf16, one 16B row per pos

    // ---- stage x tile (bf16, transposed) ----
    {
        __hip_bfloat16* xb = (__hip_bfloat16*)xT;
        for (int idx = tid; idx < CIN * NROW; idx += 512) {
            int ci = idx / NROW;
            int r  = idx - ci * NROW;
            int gp = l0 - PAD + r;
            float f = (gp >= 0 && gp < L) ? x[((size_t)b * CIN + ci) * L + gp] : 0.f;
            xb[r * CIN + ci] = __float2bfloat16(f);
        }
    }

    // ---- A fragments: 2 co-tiles (32 co rows), 9 slices = 72 VGPR ----
    const int act = __builtin_amdgcn_readfirstlane(actions[b]);
    const short8* wq = (const short8*)(bankbf + (size_t)act * COUT * KKD);
    short8 aQ[2][NSL];
    #pragma unroll
    for (int cc = 0; cc < 2; ++cc) {
        const short8* wrow = wq + ((2 * p + cc) * 16 + ln) * (KKD / 8);
        #pragma unroll
        for (int s = 0; s < NSL; ++s) aQ[cc][s] = wrow[4 * s + g];
    }

    // ---- per-lane shrink thresholds for co = (2p+cc)*16 + 4g + jj ----
    float tau[2][4];
    #pragma unroll
    for (int cc = 0; cc < 2; ++cc)
        #pragma unroll
        for (int jj = 0; jj < 4; ++jj)
            tau[cc][jj] = softplusf(threshold[(2 * p + cc) * 16 + 4 * g + jj]) + 1e-6f;

    __syncthreads();

    // ---- main loop: this wave covers local l in [q*128, q*128+128) ----
    const int wl0 = q * (TL / 4);
    for (int lt = 0; lt < (TL / 4) / 16; ++lt) {
        const int lbase = wl0 + lt * 16;
        const int row0  = lbase + ln + g;    // + 4*s per slice
        f32x4 acc[2] = {{0.f,0.f,0.f,0.f},{0.f,0.f,0.f,0.f}};
        #pragma unroll
        for (int s = 0; s < NSL; ++s) {
            short8 bfrag = xT[row0 + 4 * s];
            acc[0] = __builtin_amdgcn_mfma_f32_16x16x32_bf16(aQ[0][s], bfrag, acc[0], 0, 0, 0);
            acc[1] = __builtin_amdgcn_mfma_f32_16x16x32_bf16(aQ[1][s], bfrag, acc[1], 0, 0, 0);
        }
        // epilogue: C/D layout col = ln (l), row = 4*g + jj (co within tile)
        #pragma unroll
        for (int cc = 0; cc < 2; ++cc) {
            const int co = (2 * p + cc) * 16 + 4 * g;
            #pragma unroll
            for (int jj = 0; jj < 4; ++jj) {
                float y = acc[cc][jj];
                float r = copysignf(fmaxf(fabsf(y) - tau[cc][jj], 0.f), y);
                out[((size_t)b * COUT + co + jj) * L + l0 + lbase + ln] = r;
            }
        }
    }
}

// ---------------------------------------------------------------------------
extern "C" void kernel_launch(void* const* d_in, const int* in_sizes, int n_in,
                              void* d_out, int out_size, void* d_ws, size_t ws_size,
                              hipStream_t stream)
{
    const float* x           = (const float*)d_in[0];
    const float* superparams = (const float*)d_in[1];
    const float* threshold   = (const float*)d_in[2];
    const float* fw          = (const float*)d_in[3];
    const float* fb          = (const float*)d_in[4];
    // d_in[5..8] = value head (argmax-invariant, unused)
    const float* aw1         = (const float*)d_in[9];
    const float* ab1         = (const float*)d_in[10];
    const float* aw2         = (const float*)d_in[11];
    const float* ab2         = (const float*)d_in[12];
    float* out = (float*)d_out;

    int* actions            = (int*)d_ws;                            // 128 i32
    __hip_bfloat16* bankbf  = (__hip_bfloat16*)((char*)d_ws + 1024); // 3*64*288 bf16

    prologue_kernel<<<B + 6, 256, 0, stream>>>(
        x, fw, fb, aw1, ab1, aw2, ab2, superparams, actions, bankbf);
    conv_kernel<<<dim3(L / TL, B), 512, 0, stream>>>(
        x, bankbf, actions, threshold, out);
}

// Round 5
// 202.710 us; speedup vs baseline: 1.3088x; 1.3088x over previous
//
#include <hip/hip_runtime.h>
#include <hip/hip_bf16.h>
#include <cmath>

#define B     128
#define CIN   8
#define COUT  64
#define K     33
#define KP    36           // padded taps (288 = 9 * 32)
#define KKD   (KP * CIN)   // 288 reduction length, kk = tap*8 + ci
#define NSL   (KKD / 32)   // 9 MFMA K-slices
#define L     4096
#define PAD   16
#define HID   128
#define NW    3

#define TL    512          // l-tile per block
#define NROW  (TL + KP)    // 548 xT rows (pos range [l0-16, l0+TL+19])

typedef __attribute__((ext_vector_type(8))) short short8;
typedef __attribute__((ext_vector_type(4))) float f32x4;

__device__ __forceinline__ float softplusf(float v) {
    return (v > 20.f) ? v : log1pf(expf(v));
}

// ---------------------------------------------------------------------------
// Fused prologue: blocks 0..127 = agent (stats + MLP -> action),
//                 blocks 128..133 = wavelet bank build (bf16, padded layout).
// argmax(q) == argmax(a): value head & a.mean() are uniform across NW -> skip.
// ---------------------------------------------------------------------------
__global__ __launch_bounds__(256) void prologue_kernel(
    const float* __restrict__ x,
    const float* __restrict__ fw, const float* __restrict__ fb,
    const float* __restrict__ aw1, const float* __restrict__ ab1,
    const float* __restrict__ aw2, const float* __restrict__ ab2,
    const float* __restrict__ sp,
    int* __restrict__ actions, __hip_bfloat16* __restrict__ bankbf)
{
    const int tid = threadIdx.x;

    if (blockIdx.x < B) {
        // ---------------- agent path ----------------
        const int b = blockIdx.x;
        __shared__ float st[2 * CIN];
        __shared__ float h[HID];
        __shared__ float ha[HID];

        const int ci  = tid >> 5;
        const int sub = tid & 31;
        const float* xp = x + ((size_t)b * CIN + ci) * L;
        float s = 0.f, ss = 0.f;
        for (int j = sub; j < L / 4; j += 32) {
            float4 v = ((const float4*)xp)[j];
            s  += v.x + v.y + v.z + v.w;
            ss += v.x * v.x + v.y * v.y + v.z * v.z + v.w * v.w;
        }
        for (int m = 16; m; m >>= 1) {
            s  += __shfl_xor(s,  m);
            ss += __shfl_xor(ss, m);
        }
        if (sub == 0) {
            float mean = s / (float)L;
            float var  = fmaxf(ss - s * mean, 0.f) / (float)(L - 1);
            st[ci]       = mean;
            st[CIN + ci] = sqrtf(var);
        }
        __syncthreads();

        const int j = tid;
        if (j < HID) {
            float acc = fb[j];
            #pragma unroll
            for (int i = 0; i < 2 * CIN; ++i) acc = fmaf(st[i], fw[i * HID + j], acc);
            h[j] = fmaxf(acc, 0.f);
        }
        __syncthreads();
        if (j < HID) {
            float acc2 = ab1[j];
            for (int i = 0; i < HID; ++i) acc2 = fmaf(h[i], aw1[i * HID + j], acc2);
            ha[j] = fmaxf(acc2, 0.f);
        }
        __syncthreads();
        if (j == 0) {
            float best = -1e30f; int bi = 0;
            for (int w = 0; w < NW; ++w) {
                float a = ab2[w];
                for (int i = 0; i < HID; ++i) a = fmaf(ha[i], aw2[i * NW + w], a);
                if (a > best) { best = a; bi = w; }
            }
            actions[b] = bi;
        }
    } else {
        // ---------------- bank path ----------------
        const int t = (blockIdx.x - B) * 256 + tid;   // 6*256 = 1536 = NW*COUT*CIN
        if (t >= NW * COUT * CIN) return;
        const int nw = t >> 9;
        const int co = (t >> 3) & 63;
        const int ci = t & 7;

        const float p = sp[(co * CIN + ci) * NW + nw];
        const float scale = softplusf(p) + 1e-6f;

        float ker[K];
        float mean = 0.f;
        #pragma unroll
        for (int k = 0; k < K; ++k) {
            float g  = (float)(k - K / 2);
            float xi = g / scale;
            float v;
            if (nw == 0) {
                v = expf(-0.5f * xi * xi) * cosf(5.f * xi);
            } else if (nw == 1) {
                v = 0.8673250705840776f * (1.f - xi * xi) * expf(-0.5f * xi * xi);
            } else {
                float sgn = (g > 0.f) ? 1.f : ((g < 0.f) ? -1.f : 0.f);
                v = sgn * expf(-fabsf(xi));
            }
            ker[k] = v; mean += v;
        }
        mean *= (1.f / (float)K);
        float nrm = 0.f;
        #pragma unroll
        for (int k = 0; k < K; ++k) { ker[k] -= mean; nrm += ker[k] * ker[k]; }
        const float inv = 1.f / (sqrtf(nrm) + 1e-6f);

        __hip_bfloat16* dst = bankbf + ((size_t)(nw * COUT + co)) * KKD + ci;
        #pragma unroll
        for (int k = 0; k < K; ++k) dst[k * CIN] = __float2bfloat16(ker[k] * inv);
        #pragma unroll
        for (int k = K; k < KP; ++k) dst[k * CIN] = __float2bfloat16(0.f);
    }
}

// ---------------------------------------------------------------------------
// Conv: implicit GEMM via MFMA 16x16x32 bf16 + soft shrinkage.
//   D[l, co] = sum_kk X^T[l, kk] * W^T[kk, co],  kk = tap*8 + ci
// Operand-swapped MFMA: A = x-fragment, B = w-fragment (identical per-lane
// layouts make the swap free) -> lane (g,ln) holds 4 consecutive l for
// co = tile+ln -> float4 stores; 2 sub-tiles per iter complete 128B lines.
// 8 waves: wave w -> co-pair p = w&1 (tiles 2p,2p+1), l-quarter q = w>>1.
// ---------------------------------------------------------------------------
__global__ __launch_bounds__(512, 4) void conv_kernel(
    const float* __restrict__ x, const __hip_bfloat16* __restrict__ bankbf,
    const int* __restrict__ actions, const float* __restrict__ threshold,
    float* __restrict__ out)
{
    const int b  = blockIdx.y;
    const int l0 = blockIdx.x * TL;
    const int tid  = threadIdx.x;
    const int lane = tid & 63;
    const int w    = tid >> 6;        // wave id 0..7
    const int p    = w & 1;           // co-pair: tiles 2p, 2p+1
    const int q    = w >> 1;          // l-quarter 0..3
    const int g    = lane >> 4;       // lane group 0..3 (k-chunk / l-subrow)
    const int ln   = lane & 15;

    __shared__ short8 xT[NROW];       // [pos][ci] bf16, one 16B row per pos

    // ---- stage x tile (bf16, transposed) ----
    {
        __hip_bfloat16* xb = (__hip_bfloat16*)xT;
        for (int idx = tid; idx < CIN * NROW; idx += 512) {
            int ci = idx / NROW;
            int r  = idx - ci * NROW;
            int gp = l0 - PAD + r;
            float f = (gp >= 0 && gp < L) ? x[((size_t)b * CIN + ci) * L + gp] : 0.f;
            xb[r * CIN + ci] = __float2bfloat16(f);
        }
    }

    // ---- W fragments: 2 co-tiles (32 co rows), 9 slices = 72 VGPR ----
    const int act = __builtin_amdgcn_readfirstlane(actions[b]);
    const short8* wq = (const short8*)(bankbf + (size_t)act * COUT * KKD);
    short8 aQ[2][NSL];
    #pragma unroll
    for (int cc = 0; cc < 2; ++cc) {
        const short8* wrow = wq + ((2 * p + cc) * 16 + ln) * (KKD / 8);
        #pragma unroll
        for (int s = 0; s < NSL; ++s) aQ[cc][s] = wrow[4 * s + g];
    }

    // ---- per-lane shrink threshold: co = (2p+cc)*16 + ln ----
    float tau[2];
    #pragma unroll
    for (int cc = 0; cc < 2; ++cc)
        tau[cc] = softplusf(threshold[(2 * p + cc) * 16 + ln]) + 1e-6f;

    __syncthreads();

    // ---- main loop: this wave covers local l in [q*128, q*128+128) ----
    const int wl0 = q * (TL / 4);
    #pragma unroll
    for (int lt = 0; lt < 4; ++lt) {          // 32 l per iteration
        const int lbase = wl0 + lt * 32;
        const int r0    = lbase + ln + g;     // + 4*s per slice; +16 for sub 1
        f32x4 acc[2][2] = {{{0.f,0.f,0.f,0.f},{0.f,0.f,0.f,0.f}},
                           {{0.f,0.f,0.f,0.f},{0.f,0.f,0.f,0.f}}};
        #pragma unroll
        for (int s = 0; s < NSL; ++s) {
            short8 bf0 = xT[r0 + 4 * s];
            short8 bf1 = xT[r0 + 16 + 4 * s];
            acc[0][0] = __builtin_amdgcn_mfma_f32_16x16x32_bf16(bf0, aQ[0][s], acc[0][0], 0, 0, 0);
            acc[1][0] = __builtin_amdgcn_mfma_f32_16x16x32_bf16(bf0, aQ[1][s], acc[1][0], 0, 0, 0);
            acc[0][1] = __builtin_amdgcn_mfma_f32_16x16x32_bf16(bf1, aQ[0][s], acc[0][1], 0, 0, 0);
            acc[1][1] = __builtin_amdgcn_mfma_f32_16x16x32_bf16(bf1, aQ[1][s], acc[1][1], 0, 0, 0);
        }
        // epilogue: D[l, co]; lane (g,ln): l = lbase + 16*sub + 4g + jj, co = tile + ln
        #pragma unroll
        for (int cc = 0; cc < 2; ++cc) {
            const int co = (2 * p + cc) * 16 + ln;
            float* orow = &out[((size_t)b * COUT + co) * L + l0 + lbase + 4 * g];
            #pragma unroll
            for (int sub = 0; sub < 2; ++sub) {
                f32x4 a = acc[cc][sub];
                float4 o;
                o.x = copysignf(fmaxf(fabsf(a[0]) - tau[cc], 0.f), a[0]);
                o.y = copysignf(fmaxf(fabsf(a[1]) - tau[cc], 0.f), a[1]);
                o.z = copysignf(fmaxf(fabsf(a[2]) - tau[cc], 0.f), a[2]);
                o.w = copysignf(fmaxf(fabsf(a[3]) - tau[cc], 0.f), a[3]);
                *((float4*)(orow + 16 * sub)) = o;
            }
        }
    }
}

// ---------------------------------------------------------------------------
extern "C" void kernel_launch(void* const* d_in, const int* in_sizes, int n_in,
                              void* d_out, int out_size, void* d_ws, size_t ws_size,
                              hipStream_t stream)
{
    const float* x           = (const float*)d_in[0];
    const float* superparams = (const float*)d_in[1];
    const float* threshold   = (const float*)d_in[2];
    const float* fw          = (const float*)d_in[3];
    const float* fb          = (const float*)d_in[4];
    // d_in[5..8] = value head (argmax-invariant, unused)
    const float* aw1         = (const float*)d_in[9];
    const float* ab1         = (const float*)d_in[10];
    const float* aw2         = (const float*)d_in[11];
    const float* ab2         = (const float*)d_in[12];
    float* out = (float*)d_out;

    int* actions            = (int*)d_ws;                            // 128 i32
    __hip_bfloat16* bankbf  = (__hip_bfloat16*)((char*)d_ws + 1024); // 3*64*288 bf16

    prologue_kernel<<<B + 6, 256, 0, stream>>>(
        x, fw, fb, aw1, ab1, aw2, ab2, superparams, actions, bankbf);
    conv_kernel<<<dim3(L / TL, B), 512, 0, stream>>>(
        x, bankbf, actions, threshold, out);
}